// Round 5
// baseline (1630.328 us; speedup 1.0000x reference)
//
#include <hip/hip_runtime.h>
#include <math.h>

// Problem constants
#define VOCAB 10000
#define D 512
#define L 6
#define H 8
#define B 32
#define S 384
#define DK 64
#define DFF 2048
#define TOK (B * S)            // 12288 tokens
#define TD ((size_t)TOK * D)   // 6291456 elements per activation buffer

typedef unsigned short u16;
using bf16x8 = __attribute__((ext_vector_type(8))) short;
using f32x4  = __attribute__((ext_vector_type(4))) float;
using u16x4  = __attribute__((ext_vector_type(4))) unsigned short;

// ---------------------------------------------------------------------------
// Static workspace
__device__ float g_x[TD];                  // residual stream fp32
__device__ u16   g_h[TD];                  // LN out / attn out bf16
__device__ u16   g_q[TD];                  // Q bf16 [TOK][D]
__device__ u16   g_k[TD];                  // K bf16 [TOK][D]
__device__ u16   g_vt[TD];                 // V^T bf16 [B][H][DK][S]
__device__ u16   g_ffn[(size_t)TOK * DFF]; // FFN act bf16
__device__ u16   g_qkvT[(size_t)L * 3 * D * D];   // [L][1536][512]
__device__ u16   g_woT[(size_t)L * D * D];        // [L][512][512]
__device__ u16   g_w1T[(size_t)L * DFF * D];      // [L][2048][512]
__device__ u16   g_w2T[(size_t)L * D * DFF];      // [L][512][2048]
__device__ float g_bqkv[L * 3 * D];               // [L][1536]

__device__ __forceinline__ u16 f2bf(float f) {
  unsigned int u = __builtin_bit_cast(unsigned int, f);
  u = (u + 0x7fffu + ((u >> 16) & 1u)) >> 16;
  return (u16)u;
}

__device__ __forceinline__ void gld16(const void* g, void* l) {
  __builtin_amdgcn_global_load_lds(
      (const __attribute__((address_space(1))) unsigned int*)g,
      (__attribute__((address_space(3))) unsigned int*)l, 16, 0, 0);
}

// ---------------------------------------------------------------------------
// Embedding + intensity projection (fp32 residual stream)
__global__ __launch_bounds__(256) void embed_kernel(
    const int* __restrict__ ids, const float* __restrict__ inten,
    const float* __restrict__ emb, const float* __restrict__ iw,
    const float* __restrict__ ib, float* __restrict__ x) {
  int tok = blockIdx.x;
  int t = threadIdx.x;
  int id = ids[tok];
  float it = inten[tok];
  const float* er = emb + (size_t)id * D;
  float* xr = x + (size_t)tok * D;
  xr[t] = er[t] + it * iw[t] + ib[t];
  xr[t + 256] = er[t + 256] + it * iw[t + 256] + ib[t + 256];
}

// ---------------------------------------------------------------------------
// LayerNorm fp32 -> bf16
__global__ __launch_bounds__(256) void ln_kernel(
    const float* __restrict__ x, const float* __restrict__ w,
    const float* __restrict__ b, u16* __restrict__ out) {
  int tok = blockIdx.x;
  int t = threadIdx.x;
  const float* xr = x + (size_t)tok * D;
  float v0 = xr[t], v1 = xr[t + 256];
  float s = v0 + v1;
  float ss = v0 * v0 + v1 * v1;
  #pragma unroll
  for (int off = 32; off >= 1; off >>= 1) {
    s += __shfl_down(s, off);
    ss += __shfl_down(ss, off);
  }
  __shared__ float sbuf[4], ssbuf[4];
  int wave = t >> 6, lane = t & 63;
  if (lane == 0) { sbuf[wave] = s; ssbuf[wave] = ss; }
  __syncthreads();
  s = sbuf[0] + sbuf[1] + sbuf[2] + sbuf[3];
  ss = ssbuf[0] + ssbuf[1] + ssbuf[2] + ssbuf[3];
  float mean = s * (1.0f / (float)D);
  float var = ss * (1.0f / (float)D) - mean * mean;
  float rstd = rsqrtf(var + 1e-5f);
  u16* orow = out + (size_t)tok * D;
  orow[t]       = f2bf((v0 - mean) * rstd * w[t] + b[t]);
  orow[t + 256] = f2bf((v1 - mean) * rstd * w[t + 256] + b[t + 256]);
}

// ---------------------------------------------------------------------------
// Weight transpose+convert: src fp32 [K][N] -> dst bf16 [N][K]
__global__ __launch_bounds__(256) void transpose_cvt(
    const float* __restrict__ src, u16* __restrict__ dst,
    int K, int N, size_t sstride, size_t dstride) {
  __shared__ float tile[32][33];
  int n0 = blockIdx.x * 32, k0 = blockIdx.y * 32, l = blockIdx.z;
  src += (size_t)l * sstride;
  dst += (size_t)l * dstride;
  int tx = threadIdx.x & 31, ty = threadIdx.x >> 5;  // ty 0..7
  #pragma unroll
  for (int i = 0; i < 32; i += 8)
    tile[ty + i][tx] = src[(size_t)(k0 + ty + i) * N + n0 + tx];
  __syncthreads();
  #pragma unroll
  for (int i = 0; i < 32; i += 8)
    dst[(size_t)(n0 + ty + i) * K + k0 + tx] = f2bf(tile[tx][ty + i]);
}

__global__ __launch_bounds__(256) void concat_bias(
    const float* __restrict__ bq, const float* __restrict__ bk,
    const float* __restrict__ bv, float* __restrict__ dst) {
  int i = blockIdx.x * 256 + threadIdx.x;  // L*1536
  int l = i / 1536, c = i % 1536;
  float v = (c < 512) ? bq[l * 512 + c]
          : (c < 1024) ? bk[l * 512 + c - 512]
                       : bv[l * 512 + c - 1024];
  dst[i] = v;
}

// ---------------------------------------------------------------------------
// MFMA bf16 GEMM: C[M,N] = A[M,K] @ Bt[N,K]^T
// 128x128x32 tile. Triple-buffered LDS + counted-vmcnt pipeline (T4):
// 2 tiles always in flight (vmcnt(8) steady state), raw s_barrier only.
// T2 LDS swizzle (rule #21 both-sides): global source granule pre-permuted
// with involution g ^= (row>>1)&3, LDS dest linear, ds_read applies the same
// involution -> 16B fragment reads spread 2 lanes/bank (free) instead of 8-way.
// XCD-chunked swizzle (T1) unchanged.
// EPI 0: QKV split -> q bf16, k bf16, v^T bf16 (N=1536)
// EPI 1: residual fp32: Cres += acc + bias
// EPI 2: gelu -> bf16 (Oq)
template <int EPI>
__global__ __launch_bounds__(256) void mfma_gemm(
    const u16* __restrict__ A, const u16* __restrict__ Bt,
    const float* __restrict__ bias, float* __restrict__ Cres,
    u16* __restrict__ Oq, u16* __restrict__ Ok, u16* __restrict__ Ovt,
    int M, int N, int K) {
  __shared__ u16 As[3][128 * 32];
  __shared__ u16 Bs[3][128 * 32];
  int t = threadIdx.x;
  int lane = t & 63, w = t >> 6;
  int wr = w >> 1, wc = w & 1;

  // ---- XCD-chunked bijective remap (grid total % 8 == 0 for all shapes) ----
  int gm = gridDim.y, gn = gridDim.x;
  int wgid = blockIdx.y * gn + blockIdx.x;   // dispatch-linear id
  int xcd = wgid & 7;
  int c = wgid >> 3;
  int rpx = gm >> 3;                          // bm-rows per XCD
  int cg = c / gn;
  int bmi = xcd * rpx + cg;
  int bni = c - cg * gn;
  int bm = bmi * 128, bn = bni * 128;

  int l15 = lane & 15, l4 = lane >> 4;

  // staging: lane t covers row (t>>2), 16B granule (t&3), pre-swizzled source
  int gswu = ((t & 3) ^ ((t >> 3) & 3)) * 8;   // u16 units
  const u16* a0 = A + (size_t)(bm + (t >> 2)) * K + gswu;
  const u16* a1 = A + (size_t)(bm + 64 + (t >> 2)) * K + gswu;
  const u16* b0 = Bt + (size_t)(bn + (t >> 2)) * K + gswu;
  const u16* b1 = Bt + (size_t)(bn + 64 + (t >> 2)) * K + gswu;
  unsigned off0 = (unsigned)(t & 192) * 16u;          // wave-uniform byte base
  unsigned off1 = off0 + 256u * 16u;

  // fragment-read granule with the same involution (row>>1)&3 == (l15>>1)&3
  int rxu = (l4 ^ ((l15 >> 1) & 3)) * 8;       // u16 units

  f32x4 acc[4][4];
  #pragma unroll
  for (int mi = 0; mi < 4; ++mi)
    #pragma unroll
    for (int nj = 0; nj < 4; ++nj)
      acc[mi][nj] = f32x4{0.f, 0.f, 0.f, 0.f};

  int nt = K >> 5;  // K-steps of 32 (>= 16 for all our shapes)

#define STAGE_T(ti, bi) do { int k0s = (ti) * 32;            \
    gld16(a0 + k0s, (char*)As[bi] + off0);                   \
    gld16(a1 + k0s, (char*)As[bi] + off1);                   \
    gld16(b0 + k0s, (char*)Bs[bi] + off0);                   \
    gld16(b1 + k0s, (char*)Bs[bi] + off1); } while (0)

  // prologue: stage tiles 0,1,2 (12 loads in flight per wave)
  STAGE_T(0, 0);
  STAGE_T(1, 1);
  STAGE_T(2, 2);

  int cur = 0;
  for (int tt = 0; tt < nt; ++tt) {
    int rem = nt - tt;
    // outstanding = 4*min(rem,3); wait until tile tt's 4 loads landed
    if (rem > 2)       asm volatile("s_waitcnt vmcnt(8)" ::: "memory");
    else if (rem == 2) asm volatile("s_waitcnt vmcnt(4)" ::: "memory");
    else               asm volatile("s_waitcnt vmcnt(0)" ::: "memory");
    __builtin_amdgcn_s_barrier();          // all waves' tile-tt loads landed
    __builtin_amdgcn_sched_barrier(0);     // pin ds_reads below the barrier
    const u16* Asb = As[cur];
    const u16* Bsb = Bs[cur];
    bf16x8 af[4], bfr[4];
    #pragma unroll
    for (int mi = 0; mi < 4; ++mi)
      af[mi] = *(const bf16x8*)(Asb + (wr * 64 + mi * 16 + l15) * 32 + rxu);
    #pragma unroll
    for (int nj = 0; nj < 4; ++nj)
      bfr[nj] = *(const bf16x8*)(Bsb + (wc * 64 + nj * 16 + l15) * 32 + rxu);
    #pragma unroll
    for (int mi = 0; mi < 4; ++mi)
      #pragma unroll
      for (int nj = 0; nj < 4; ++nj)
        acc[mi][nj] = __builtin_amdgcn_mfma_f32_16x16x32_bf16(af[mi], bfr[nj], acc[mi][nj], 0, 0, 0);
    __builtin_amdgcn_sched_barrier(0);     // pin reads+MFMA above barrier
    __builtin_amdgcn_s_barrier();          // all waves done reading buf[cur]
    if (tt + 3 < nt) STAGE_T(tt + 3, cur);
    cur = (cur == 2) ? 0 : cur + 1;
  }
#undef STAGE_T

  int row00 = bm + wr * 64, col0 = bn + wc * 64;
  #pragma unroll
  for (int mi = 0; mi < 4; ++mi) {
    int rowb = row00 + mi * 16 + l4 * 4;
    #pragma unroll
    for (int nj = 0; nj < 4; ++nj) {
      int col = col0 + nj * 16 + l15;
      float bcol = bias[col];
      if (EPI == 0) {
        if (col < 512) {
          #pragma unroll
          for (int r = 0; r < 4; ++r)
            Oq[(size_t)(rowb + r) * D + col] = f2bf(acc[mi][nj][r] + bcol);
        } else if (col < 1024) {
          #pragma unroll
          for (int r = 0; r < 4; ++r)
            Ok[(size_t)(rowb + r) * D + (col - 512)] = f2bf(acc[mi][nj][r] + bcol);
        } else {
          int cv = col - 1024;
          int hh = cv >> 6, dk = cv & 63;
          int bb = rowb / S, ss = rowb - bb * S;
          u16x4 pk;
          #pragma unroll
          for (int r = 0; r < 4; ++r) pk[r] = f2bf(acc[mi][nj][r] + bcol);
          *(u16x4*)(Ovt + ((size_t)(bb * H + hh) * DK + dk) * S + ss) = pk;
        }
      } else if (EPI == 1) {
        #pragma unroll
        for (int r = 0; r < 4; ++r) {
          size_t ci = (size_t)(rowb + r) * N + col;
          Cres[ci] += acc[mi][nj][r] + bcol;
        }
      } else {  // GELU -> bf16
        #pragma unroll
        for (int r = 0; r < 4; ++r) {
          float v = acc[mi][nj][r] + bcol;
          v = 0.5f * v * (1.0f + erff(v * 0.70710678118654752f));
          Oq[(size_t)(rowb + r) * N + col] = f2bf(v);
        }
      }
    }
  }
}

// ---------------------------------------------------------------------------
// MFMA flash attention. Grid: (B*H, S/128). 4 waves x 32 queries.
__global__ __launch_bounds__(256) void attn_mfma(
    const u16* __restrict__ q, const u16* __restrict__ k,
    const u16* __restrict__ vt, const int* __restrict__ ids,
    u16* __restrict__ out) {
  __shared__ u16 Ks[64][72];
  __shared__ u16 Vs[64][72];   // V^T tile: [dk][key]
  __shared__ u16 Ps[4][32][72];
  __shared__ float Ms[64];
  int t = threadIdx.x, lane = t & 63, w = t >> 6;
  int l15 = lane & 15, l4 = lane >> 4;
  int bh = blockIdx.x;
  int b = bh >> 3, hh = bh & 7;
  int q0 = blockIdx.y * 128 + w * 32;

  // Preload Q fragments (2 m-frags x 2 k-steps)
  bf16x8 qf[2][2];
  const u16* qbase = q + (size_t)(b * S + q0) * D + hh * DK;
  #pragma unroll
  for (int mi = 0; mi < 2; ++mi)
    #pragma unroll
    for (int ks = 0; ks < 2; ++ks)
      qf[mi][ks] = *(const bf16x8*)(qbase + (size_t)(mi * 16 + l15) * D + ks * 32 + l4 * 8);

  float m[8], lsum[8];
  f32x4 accO[2][4];
  #pragma unroll
  for (int i = 0; i < 8; ++i) { m[i] = -3e38f; lsum[i] = 0.f; }
  #pragma unroll
  for (int mi = 0; mi < 2; ++mi)
    #pragma unroll
    for (int nj = 0; nj < 4; ++nj)
      accO[mi][nj] = f32x4{0.f, 0.f, 0.f, 0.f};

  for (int kb = 0; kb < S; kb += 64) {
    __syncthreads();
    #pragma unroll
    for (int i = 0; i < 2; ++i) {
      int slot = i * 256 + t;
      int rr = slot >> 3, ch = slot & 7;
      *(bf16x8*)(&Ks[rr][ch * 8]) =
          *(const bf16x8*)(k + (size_t)(b * S + kb + rr) * D + hh * DK + ch * 8);
      *(bf16x8*)(&Vs[rr][ch * 8]) =
          *(const bf16x8*)(vt + ((size_t)(b * H + hh) * DK + rr) * S + kb + ch * 8);
    }
    if (t < 64) Ms[t] = (ids[b * S + kb + t] == 0) ? -1e9f : 0.0f;
    __syncthreads();

    // QK^T
    f32x4 sc[2][4];
    #pragma unroll
    for (int mi = 0; mi < 2; ++mi)
      #pragma unroll
      for (int nj = 0; nj < 4; ++nj)
        sc[mi][nj] = f32x4{0.f, 0.f, 0.f, 0.f};
    #pragma unroll
    for (int ks = 0; ks < 2; ++ks) {
      bf16x8 kf[4];
      #pragma unroll
      for (int nj = 0; nj < 4; ++nj)
        kf[nj] = *(const bf16x8*)(&Ks[nj * 16 + l15][ks * 32 + l4 * 8]);
      #pragma unroll
      for (int mi = 0; mi < 2; ++mi)
        #pragma unroll
        for (int nj = 0; nj < 4; ++nj)
          sc[mi][nj] = __builtin_amdgcn_mfma_f32_16x16x32_bf16(qf[mi][ks], kf[nj], sc[mi][nj], 0, 0, 0);
    }
    // scale + mask
    #pragma unroll
    for (int mi = 0; mi < 2; ++mi)
      #pragma unroll
      for (int nj = 0; nj < 4; ++nj) {
        float mv = Ms[nj * 16 + l15];
        #pragma unroll
        for (int r = 0; r < 4; ++r)
          sc[mi][nj][r] = sc[mi][nj][r] * 0.125f + mv;
      }
    // online softmax (rows live in lanes with same l4)
    #pragma unroll
    for (int mi = 0; mi < 2; ++mi)
      #pragma unroll
      for (int r = 0; r < 4; ++r) {
        int ridx = mi * 4 + r;
        float mx = sc[mi][0][r];
        #pragma unroll
        for (int nj = 1; nj < 4; ++nj) mx = fmaxf(mx, sc[mi][nj][r]);
        #pragma unroll
        for (int o = 1; o < 16; o <<= 1) mx = fmaxf(mx, __shfl_xor(mx, o));
        float mnew = fmaxf(m[ridx], mx);
        float scale = __expf(m[ridx] - mnew);
        float rs = 0.f;
        #pragma unroll
        for (int nj = 0; nj < 4; ++nj) {
          float p = __expf(sc[mi][nj][r] - mnew);
          sc[mi][nj][r] = p;
          rs += p;
        }
        #pragma unroll
        for (int o = 1; o < 16; o <<= 1) rs += __shfl_xor(rs, o);
        lsum[ridx] = lsum[ridx] * scale + rs;
        m[ridx] = mnew;
        #pragma unroll
        for (int nj = 0; nj < 4; ++nj) accO[mi][nj][r] *= scale;
      }
    // P -> bf16 -> wave-private LDS
    #pragma unroll
    for (int mi = 0; mi < 2; ++mi)
      #pragma unroll
      for (int nj = 0; nj < 4; ++nj)
        #pragma unroll
        for (int r = 0; r < 4; ++r)
          Ps[w][mi * 16 + l4 * 4 + r][nj * 16 + l15] = f2bf(sc[mi][nj][r]);
    // PV
    #pragma unroll
    for (int ks2 = 0; ks2 < 2; ++ks2) {
      bf16x8 pf[2], vf[4];
      #pragma unroll
      for (int mi = 0; mi < 2; ++mi)
        pf[mi] = *(const bf16x8*)(&Ps[w][mi * 16 + l15][ks2 * 32 + l4 * 8]);
      #pragma unroll
      for (int nj = 0; nj < 4; ++nj)
        vf[nj] = *(const bf16x8*)(&Vs[nj * 16 + l15][ks2 * 32 + l4 * 8]);
      #pragma unroll
      for (int mi = 0; mi < 2; ++mi)
        #pragma unroll
        for (int nj = 0; nj < 4; ++nj)
          accO[mi][nj] = __builtin_amdgcn_mfma_f32_16x16x32_bf16(pf[mi], vf[nj], accO[mi][nj], 0, 0, 0);
    }
  }

  // output bf16 [TOK][D]
  #pragma unroll
  for (int mi = 0; mi < 2; ++mi)
    #pragma unroll
    for (int nj = 0; nj < 4; ++nj)
      #pragma unroll
      for (int r = 0; r < 4; ++r) {
        int row = b * S + q0 + mi * 16 + l4 * 4 + r;
        out[(size_t)row * D + hh * DK + nj * 16 + l15] =
            f2bf(accO[mi][nj][r] / lsum[mi * 4 + r]);
      }
}

// ---------------------------------------------------------------------------
__global__ __launch_bounds__(512) void pool_kernel(
    const float* __restrict__ x, const float* __restrict__ inten,
    float* __restrict__ out) {
  int b = blockIdx.x;
  int d = threadIdx.x;
  float acc = 0.f;
  for (int s = 0; s < S; ++s)
    acc += inten[b * S + s] * x[((size_t)b * S + s) * D + d];
  out[b * D + d] = acc;
}

// ---------------------------------------------------------------------------
extern "C" void kernel_launch(void* const* d_in, const int* in_sizes, int n_in,
                              void* d_out, int out_size, void* d_ws, size_t ws_size,
                              hipStream_t stream) {
  const int* input_id    = (const int*)d_in[0];
  const float* intensity = (const float*)d_in[1];
  const float* emb = (const float*)d_in[2];
  const float* iw  = (const float*)d_in[3];
  const float* ib  = (const float*)d_in[4];
  const float* Wq  = (const float*)d_in[5];
  const float* bq  = (const float*)d_in[6];
  const float* Wk  = (const float*)d_in[7];
  const float* bk  = (const float*)d_in[8];
  const float* Wv  = (const float*)d_in[9];
  const float* bv  = (const float*)d_in[10];
  const float* Wo  = (const float*)d_in[11];
  const float* bo  = (const float*)d_in[12];
  const float* ln1w = (const float*)d_in[13];
  const float* ln1b = (const float*)d_in[14];
  const float* ln2w = (const float*)d_in[15];
  const float* ln2b = (const float*)d_in[16];
  const float* W1  = (const float*)d_in[17];
  const float* b1  = (const float*)d_in[18];
  const float* W2  = (const float*)d_in[19];
  const float* b2  = (const float*)d_in[20];
  float* outp = (float*)d_out;

  float *x, *bqkv;
  u16 *h, *q, *k, *vt, *ffn, *qkvT, *woT, *w1T, *w2T;
  { void* p; hipGetSymbolAddress(&p, HIP_SYMBOL(g_x));    x    = (float*)p; }
  { void* p; hipGetSymbolAddress(&p, HIP_SYMBOL(g_h));    h    = (u16*)p; }
  { void* p; hipGetSymbolAddress(&p, HIP_SYMBOL(g_q));    q    = (u16*)p; }
  { void* p; hipGetSymbolAddress(&p, HIP_SYMBOL(g_k));    k    = (u16*)p; }
  { void* p; hipGetSymbolAddress(&p, HIP_SYMBOL(g_vt));   vt   = (u16*)p; }
  { void* p; hipGetSymbolAddress(&p, HIP_SYMBOL(g_ffn));  ffn  = (u16*)p; }
  { void* p; hipGetSymbolAddress(&p, HIP_SYMBOL(g_qkvT)); qkvT = (u16*)p; }
  { void* p; hipGetSymbolAddress(&p, HIP_SYMBOL(g_woT));  woT  = (u16*)p; }
  { void* p; hipGetSymbolAddress(&p, HIP_SYMBOL(g_w1T));  w1T  = (u16*)p; }
  { void* p; hipGetSymbolAddress(&p, HIP_SYMBOL(g_w2T));  w2T  = (u16*)p; }
  { void* p; hipGetSymbolAddress(&p, HIP_SYMBOL(g_bqkv)); bqkv = (float*)p; }

  // ---- weight prep (per launch; deterministic) ----
  dim3 t256(256);
  transpose_cvt<<<dim3(16, 16, L), t256, 0, stream>>>(Wq, qkvT + 0 * D * D, D, D, (size_t)D * D, (size_t)3 * D * D);
  transpose_cvt<<<dim3(16, 16, L), t256, 0, stream>>>(Wk, qkvT + 1 * D * D, D, D, (size_t)D * D, (size_t)3 * D * D);
  transpose_cvt<<<dim3(16, 16, L), t256, 0, stream>>>(Wv, qkvT + 2 * D * D, D, D, (size_t)D * D, (size_t)3 * D * D);
  transpose_cvt<<<dim3(16, 16, L), t256, 0, stream>>>(Wo, woT, D, D, (size_t)D * D, (size_t)D * D);
  transpose_cvt<<<dim3(64, 16, L), t256, 0, stream>>>(W1, w1T, D, DFF, (size_t)D * DFF, (size_t)D * DFF);
  transpose_cvt<<<dim3(16, 64, L), t256, 0, stream>>>(W2, w2T, DFF, D, (size_t)DFF * D, (size_t)DFF * D);
  concat_bias<<<L * 3 * D / 256, t256, 0, stream>>>(bq, bk, bv, bqkv);

  embed_kernel<<<TOK, t256, 0, stream>>>(input_id, intensity, emb, iw, ib, x);

  for (int l = 0; l < L; ++l) {
    const u16* qkvT_l = qkvT + (size_t)l * 3 * D * D;
    const u16* woT_l  = woT + (size_t)l * D * D;
    const u16* w1T_l  = w1T + (size_t)l * D * DFF;
    const u16* w2T_l  = w2T + (size_t)l * DFF * D;

    ln_kernel<<<TOK, t256, 0, stream>>>(x, ln1w + (size_t)l * D, ln1b + (size_t)l * D, h);
    mfma_gemm<0><<<dim3(12, 96), t256, 0, stream>>>(h, qkvT_l, bqkv + l * 3 * D,
                                                    nullptr, q, k, vt, TOK, 3 * D, D);
    attn_mfma<<<dim3(B * H, S / 128), t256, 0, stream>>>(q, k, vt, input_id, h);
    mfma_gemm<1><<<dim3(4, 96), t256, 0, stream>>>(h, woT_l, bo + (size_t)l * D,
                                                   x, nullptr, nullptr, nullptr, TOK, D, D);
    ln_kernel<<<TOK, t256, 0, stream>>>(x, ln2w + (size_t)l * D, ln2b + (size_t)l * D, h);
    mfma_gemm<2><<<dim3(16, 96), t256, 0, stream>>>(h, w1T_l, b1 + (size_t)l * DFF,
                                                    nullptr, ffn, nullptr, nullptr, TOK, DFF, D);
    mfma_gemm<1><<<dim3(4, 96), t256, 0, stream>>>(ffn, w2T_l, b2 + (size_t)l * D,
                                                   x, nullptr, nullptr, nullptr, TOK, D, DFF);
  }

  pool_kernel<<<B, 512, 0, stream>>>(x, intensity, outp);
}